// Round 5
// baseline (271.394 us; speedup 1.0000x reference)
//
#include <hip/hip_runtime.h>
#include <hip/hip_bf16.h>
#include <math.h>

// Problem constants
#define B_SZ   4
#define T_LEN  2048
#define DM     1024
#define NH     16
#define DH     64
#define INNER  1024          // NH*DH
#define NROWS  (B_SZ*T_LEN)  // 8192
#define NQ     (NROWS*INNER) // elements per Q/K/V/Y buffer
#define CH     64            // chunk length
#define NCH    (T_LEN/CH)    // 32 chunks

typedef __bf16 bf16x8 __attribute__((ext_vector_type(8)));
typedef __bf16 bf16x4 __attribute__((ext_vector_type(4)));
typedef float  f32x4  __attribute__((ext_vector_type(4)));
typedef __attribute__((address_space(3))) void*       lds_vp;
typedef const __attribute__((address_space(1))) void* gbl_vp;

// Swizzled index into a 64x64 bf16 LDS tile: 8-elem blocks rotated by row>>2.
__device__ __forceinline__ int swz(int row, int col) {
    return (row << 6) + ((((col >> 3) + (row >> 2)) & 7) << 3) + (col & 7);
}

// ---------------------------------------------------------------------------
// Weight transpose + cast: W (K x N fp32, row-major) -> WT (N x K bf16).
// ---------------------------------------------------------------------------
__global__ __launch_bounds__(256) void wt_cast_transpose(const float* __restrict__ Wq,
                                                         const float* __restrict__ Wk,
                                                         const float* __restrict__ Wv,
                                                         const float* __restrict__ Wo,
                                                         __bf16* __restrict__ WqT,
                                                         __bf16* __restrict__ WkT,
                                                         __bf16* __restrict__ WvT,
                                                         __bf16* __restrict__ WoT) {
    __shared__ float tile[64][65];
    const float* W;
    __bf16* WT;
    if      (blockIdx.z == 0) { W = Wq; WT = WqT; }
    else if (blockIdx.z == 1) { W = Wk; WT = WkT; }
    else if (blockIdx.z == 2) { W = Wv; WT = WvT; }
    else                      { W = Wo; WT = WoT; }

    const int k0 = blockIdx.y * 64, n0 = blockIdx.x * 64;
    const int tr  = threadIdx.x >> 4;        // 0..15
    const int tc4 = (threadIdx.x & 15) * 4;  // 0..60

#pragma unroll
    for (int r = 0; r < 4; r++) {
        const int k = tr + 16 * r;
        const float4 v = *(const float4*)(W + (size_t)(k0 + k) * DM + n0 + tc4);
        tile[k][tc4 + 0] = v.x;
        tile[k][tc4 + 1] = v.y;
        tile[k][tc4 + 2] = v.z;
        tile[k][tc4 + 3] = v.w;
    }
    __syncthreads();
#pragma unroll
    for (int r = 0; r < 4; r++) {
        const int n = tr + 16 * r;
        bf16x4 o;
#pragma unroll
        for (int j = 0; j < 4; j++) o[j] = (__bf16)tile[tc4 + j][n];
        *(bf16x4*)(WT + (size_t)(n0 + n) * DM + k0 + tc4) = o;
    }
}

// ---------------------------------------------------------------------------
// v2 GEMM: m201-anatomy 4-phase/iter pipeline, half-tile-slot LDS.
//   C[m0:+128][n0c:+256] = A[m0:+128][0:1024] * BT[n0bt:+256][0:1024]^T
//   512 threads = 8 waves (2M x 4N), per-wave 64x64 (acc 4x4):
//     per phase: 8 swizzled ds_read_b128 || stage ONE K-half pair (3
//     global_load_lds) -> barrier -> lgkmcnt(0)+sched_barrier ->
//     setprio(1) 16 MFMA -> [vmcnt(3) every 2nd phase] -> barrier.
//   LDS = 8 slots: A[buf][ks] 8KB + B[buf][ks] 16KB = 96 KiB, 1 block/CU.
//   Slot ledger (iter i, kb = 128*i elems):
//     p0: rd(b0,ks0)  stg (b1,ks1)<-kb+96   [read @p3, lead 3]
//     p1: rd(b0,ks1)  stg (b0,ks0)<-kb+128  [read @next p0]  vmcnt(3)
//     p2: rd(b1,ks0)  stg (b0,ks1)<-kb+160  [read @next p1]
//     p3: rd(b1,ks1)  stg (b1,ks0)<-kb+192  [read @next p2]  vmcnt(3)
//   Every read's staging is >=1 full phase retired before use; counted
//   vmcnt never drains mid-loop (T4).  Swizzle both sides (rule 21).
// ---------------------------------------------------------------------------
#define GV2_A(b_, k_) (((b_) * 2 + (k_)) * 8192)
#define GV2_B(b_, k_) (32768 + ((b_) * 2 + (k_)) * 16384)

template <typename CT>
__device__ __forceinline__ void gemm_v2_body(const __bf16* __restrict__ A,
                                             const __bf16* __restrict__ BT,
                                             CT* __restrict__ C,
                                             int m0, int n0bt, int n0c) {
    __shared__ __align__(16) char lds[98304];

    const int tid  = threadIdx.x;
    const int wid  = tid >> 6;       // 0..7
    const int lane = tid & 63;
    const int wm = wid >> 2;         // 0..1 : 64-row stripe
    const int wn = wid & 3;          // 0..3 : 64-col stripe
    const int frow = lane & 15, quad = lane >> 4;

    // swizzled ds_read byte offsets within a slot (loop-invariant)
    const int xo = (quad ^ (frow & 3)) << 4;
    int offA[4], offB[4];
#pragma unroll
    for (int j = 0; j < 4; ++j) {
        offA[j] = (wm * 64 + j * 16 + frow) * 64 + xo;
        offB[j] = (wn * 64 + j * 16 + frow) * 64 + xo;
    }

    // staging: per-lane pre-swizzled global source; LDS dest linear
    const int srow = tid >> 2;                           // 0..127
    const int scol = (((tid & 3) ^ (srow & 3)) << 3);    // elem col (swz)
    const __bf16* srcA  = A  + (size_t)(m0 + srow) * 1024 + scol;
    const __bf16* srcB0 = BT + (size_t)(n0bt + srow) * 1024 + scol;
    const __bf16* srcB1 = BT + (size_t)(n0bt + 128 + srow) * 1024 + scol;

    // stage one (A+B) K-half pair: 3 global_load_lds
#define STGP(as_, bs_, koff_) do {                                                 \
        __builtin_amdgcn_global_load_lds((gbl_vp)(srcA  + (koff_)),                \
            (lds_vp)(lds + (as_) + wid * 1024), 16, 0, 0);                         \
        __builtin_amdgcn_global_load_lds((gbl_vp)(srcB0 + (koff_)),                \
            (lds_vp)(lds + (bs_) + wid * 1024), 16, 0, 0);                         \
        __builtin_amdgcn_global_load_lds((gbl_vp)(srcB1 + (koff_)),                \
            (lds_vp)(lds + (bs_) + 8192 + wid * 1024), 16, 0, 0);                  \
    } while (0)

#define VM3 asm volatile("s_waitcnt vmcnt(3)" ::: "memory")
#define VM0 asm volatile("s_waitcnt vmcnt(0)" ::: "memory")

    f32x4 acc[4][4];
#pragma unroll
    for (int i = 0; i < 4; i++)
#pragma unroll
        for (int j = 0; j < 4; j++) acc[i][j] = (f32x4)0.f;

    // prologue: t0 both halves + t1.ks0 (9 loads); retire t0 (vmcnt(3))
    STGP(GV2_A(0, 0), GV2_B(0, 0), 0);
    STGP(GV2_A(0, 1), GV2_B(0, 1), 32);
    STGP(GV2_A(1, 0), GV2_B(1, 0), 64);
    VM3;
    asm volatile("s_barrier" ::: "memory");

#define PH(as_, bs_, STG_STMT, VM_STMT)                                            \
    {                                                                              \
        const char* Ab_ = lds + (as_);                                             \
        const char* Bb_ = lds + (bs_);                                             \
        bf16x8 af_[4], bf_[4];                                                     \
        _Pragma("unroll")                                                          \
        for (int j_ = 0; j_ < 4; ++j_) {                                           \
            af_[j_] = *(const bf16x8*)(Ab_ + offA[j_]);                            \
            bf_[j_] = *(const bf16x8*)(Bb_ + offB[j_]);                            \
        }                                                                          \
        STG_STMT;                                                                  \
        asm volatile("s_barrier" ::: "memory");                                    \
        asm volatile("s_waitcnt lgkmcnt(0)" ::: "memory");                         \
        __builtin_amdgcn_sched_barrier(0);                                         \
        __builtin_amdgcn_s_setprio(1);                                             \
        _Pragma("unroll")                                                          \
        for (int mi_ = 0; mi_ < 4; ++mi_)                                          \
            _Pragma("unroll")                                                      \
            for (int nj_ = 0; nj_ < 4; ++nj_)                                      \
                acc[mi_][nj_] = __builtin_amdgcn_mfma_f32_16x16x32_bf16(           \
                    af_[mi_], bf_[nj_], acc[mi_][nj_], 0, 0, 0);                   \
        __builtin_amdgcn_s_setprio(0);                                             \
        VM_STMT;                                                                   \
        asm volatile("s_barrier" ::: "memory");                                    \
    }

    // main loop: iters 0..6 (tiles 2i, 2i+1); tail iter 7 drains
    for (int i = 0; i < 7; ++i) {
        const int kb = i * 128;
        PH(GV2_A(0, 0), GV2_B(0, 0), STGP(GV2_A(1, 1), GV2_B(1, 1), kb + 96), );
        PH(GV2_A(0, 1), GV2_B(0, 1), STGP(GV2_A(0, 0), GV2_B(0, 0), kb + 128), VM3);
        PH(GV2_A(1, 0), GV2_B(1, 0), STGP(GV2_A(0, 1), GV2_B(0, 1), kb + 160), );
        PH(GV2_A(1, 1), GV2_B(1, 1), STGP(GV2_A(1, 0), GV2_B(1, 0), kb + 192), VM3);
    }
    // tail: tiles 14,15 (kb = 896); stage t15.ks1 then drain
    PH(GV2_A(0, 0), GV2_B(0, 0), STGP(GV2_A(1, 1), GV2_B(1, 1), 992), );
    PH(GV2_A(0, 1), GV2_B(0, 1), , VM0);
    PH(GV2_A(1, 0), GV2_B(1, 0), , );
    PH(GV2_A(1, 1), GV2_B(1, 1), , );

#undef PH
#undef STGP
#undef VM3
#undef VM0

    // epilogue: C-write (same fragment mapping as verified base kernel)
    const int cr = quad * 4, cc = frow;
#pragma unroll
    for (int mi = 0; mi < 4; ++mi) {
#pragma unroll
        for (int nj = 0; nj < 4; ++nj) {
            CT* Cp = C + (size_t)(m0 + wm * 64 + mi * 16 + cr) * 1024
                       + n0c + wn * 64 + nj * 16 + cc;
#pragma unroll
            for (int r = 0; r < 4; r++) Cp[(size_t)r * 1024] = (CT)acc[mi][nj][r];
        }
    }
}

// Fused QKV: BTall = [WqT|WkT|WvT] as [3072][1024]; QKV = [Q|K|V] contiguous.
// 64 m-tiles x 12 n-tiles = 768 blocks = exactly 3 rounds at 1 block/CU.
// XCD swizzle (T1, bijective: 768 % 8 == 0).
__global__ __launch_bounds__(512, 1) void qkv_gemm_v2(const __bf16* __restrict__ xb,
                                                      const __bf16* __restrict__ BTall,
                                                      __bf16* __restrict__ QKV) {
    const int id = blockIdx.x;
    const int wg = (id & 7) * 96 + (id >> 3);
    const int mt = wg / 12, nt = wg % 12;
    const int mat = nt >> 2;
    gemm_v2_body<__bf16>(xb, BTall, QKV + (size_t)mat * NQ,
                         mt * 128, nt * 256, (nt & 3) * 256);
}

// Output projection: 64 x 4 = 256 blocks = exactly 1 round.
__global__ __launch_bounds__(512, 1) void out_gemm_v2(const __bf16* __restrict__ Yb,
                                                      const __bf16* __restrict__ WoT,
                                                      float* __restrict__ Cout) {
    const int id = blockIdx.x;
    const int wg = (id & 7) * 32 + (id >> 3);
    const int mt = wg >> 2, nt = wg & 3;
    gemm_v2_body<float>(Yb, WoT, Cout, mt * 128, nt * 256, nt * 256);
}

// ---------------------------------------------------------------------------
// Fused gates + x cast (MFMA).  128 blocks x 256 thr; block = 64 rows.
// ---------------------------------------------------------------------------
#define WGS 1032   // lWg row stride (bf16): 516 dw, 4-dw bank rotation
#define LAS 40     // lA row stride (bf16): 20 dw rotation, 16B aligned
__global__ __launch_bounds__(256) void gates_fused(const float* __restrict__ x,
                                                   const float* __restrict__ Wa,
                                                   const float* __restrict__ ba,
                                                   const float* __restrict__ Wb,
                                                   const float* __restrict__ bb,
                                                   float* __restrict__ AlphaT,
                                                   float* __restrict__ BetaT,
                                                   __bf16* __restrict__ xb) {
    __shared__ __align__(16) __bf16 lWg[32 * WGS];
    __shared__ __align__(16) __bf16 lA[64 * LAS];

    const int tid = threadIdx.x;
    const int wid = tid >> 6, lane = tid & 63;
    const int quad = lane >> 4, frow = lane & 15;
    const int m0 = blockIdx.x * 64;

    // ---- stage W^T (bf16) into LDS ----
    {
        const int kbase = tid * 4;
#pragma unroll
        for (int j = 0; j < 4; j++) {
            const int k = kbase + j;
            const float4* war = (const float4*)(Wa + (size_t)k * NH);
            const float4* wbr = (const float4*)(Wb + (size_t)k * NH);
#pragma unroll
            for (int q = 0; q < 4; q++) {
                const float4 a = war[q], bq = wbr[q];
                lWg[(q * 4 + 0) * WGS + k] = (__bf16)a.x;
                lWg[(q * 4 + 1) * WGS + k] = (__bf16)a.y;
                lWg[(q * 4 + 2) * WGS + k] = (__bf16)a.z;
                lWg[(q * 4 + 3) * WGS + k] = (__bf16)a.w;
                lWg[(16 + q * 4 + 0) * WGS + k] = (__bf16)bq.x;
                lWg[(16 + q * 4 + 1) * WGS + k] = (__bf16)bq.y;
                lWg[(16 + q * 4 + 2) * WGS + k] = (__bf16)bq.z;
                lWg[(16 + q * 4 + 3) * WGS + k] = (__bf16)bq.w;
            }
        }
    }
    const float bias_a = ba[frow];
    const float bias_b = bb[frow];

    // ---- pipelined K loop ----
    const int rrow = tid >> 2;          // 0..63
    const int rk   = (tid & 3) * 8;     // 0,8,16,24
    const float* xrow = x + (size_t)(m0 + rrow) * DM + rk;
    float4 c0 = *(const float4*)(xrow + 0);
    float4 c1 = *(const float4*)(xrow + 4);

    f32x4 acc[2];
    acc[0] = (f32x4)0.f; acc[1] = (f32x4)0.f;

    for (int k0 = 0; k0 < DM; k0 += 32) {
        __syncthreads();   // prev iter's lA reads done (also covers lWg stage)
        bf16x8 xv;
        xv[0] = (__bf16)c0.x; xv[1] = (__bf16)c0.y; xv[2] = (__bf16)c0.z; xv[3] = (__bf16)c0.w;
        xv[4] = (__bf16)c1.x; xv[5] = (__bf16)c1.y; xv[6] = (__bf16)c1.z; xv[7] = (__bf16)c1.w;
        *(bf16x8*)&lA[rrow * LAS + rk] = xv;
        *(bf16x8*)(xb + (size_t)(m0 + rrow) * DM + k0 + rk) = xv;
        if (k0 + 32 < DM) {
            c0 = *(const float4*)(xrow + k0 + 32);
            c1 = *(const float4*)(xrow + k0 + 36);
        }
        __syncthreads();
        const bf16x8 af = *(const bf16x8*)&lA[(wid * 16 + frow) * LAS + quad * 8];
#pragma unroll
        for (int ct = 0; ct < 2; ct++) {
            const bf16x8 bf = *(const bf16x8*)&lWg[(ct * 16 + frow) * WGS + k0 + quad * 8];
            acc[ct] = __builtin_amdgcn_mfma_f32_16x16x32_bf16(af, bf, acc[ct], 0, 0, 0);
        }
    }

    // ---- sigmoid epilogue, transposed store ----
#pragma unroll
    for (int ct = 0; ct < 2; ct++) {
        const float bias = (ct == 0) ? bias_a : bias_b;
        float* dst = (ct == 0) ? AlphaT : BetaT;
#pragma unroll
        for (int r = 0; r < 4; r++) {
            const int row = m0 + wid * 16 + quad * 4 + r;
            const float s = acc[ct][r] + bias;
            dst[(size_t)frow * NROWS + row] = 1.f / (1.f + __expf(-s));
        }
    }
}

// ---------------------------------------------------------------------------
// Pass A (MFMA, bf16 I/O): per (b,h,c), 256 threads = 4 waves.
//   G = Q K^T ; A = mask*exp(la_t-la_s)*b_s*G ; Y_intra = A V -> V (bf16)
//   dS^T[j][i] -> DS (fp32, transposed for state_y).
// ---------------------------------------------------------------------------
__global__ __launch_bounds__(256) void chunk_ds(const __bf16* __restrict__ Q,
                                                const __bf16* __restrict__ K,
                                                __bf16* __restrict__ V,
                                                const float* __restrict__ AlphaT,
                                                const float* __restrict__ BetaT,
                                                float* __restrict__ Dec,
                                                float* __restrict__ DS,
                                                float* __restrict__ ExpT) {
    __shared__ __align__(16) __bf16 Qb[64 * 64];
    __shared__ __align__(16) __bf16 Kb[64 * 64];
    __shared__ __align__(16) __bf16 KTs[64 * 64];  // [j][s] = swd_s * kn[s][j]
    __shared__ __align__(16) __bf16 VTb[64 * 64];  // [i][s] = V[s][i]
    __shared__ __align__(16) __bf16 Ab[64 * 64];   // [t][s]
    __shared__ float sla[64], sb[64], swd[64];

    const int blk = blockIdx.x;
    const int c = blk & 31, h = (blk >> 5) & 15, b = blk >> 9;
    const int t0 = c * CH;
    const int tid = threadIdx.x;
    const int wid = tid >> 6, lane = tid & 63;
    const size_t rowbase = ((size_t)(b * T_LEN + t0) * NH + h) * DH;

    // prefetch (16B bf16x8 per matrix per round)
    const int srow = tid >> 3;          // 0..31
    const int scol = (tid & 7) * 8;     // 0..56
    bf16x8 q8[2], k8[2], v8[2];
#pragma unroll
    for (int r = 0; r < 2; r++) {
        const size_t g = rowbase + (size_t)(srow + 32 * r) * INNER + scol;
        q8[r] = *(const bf16x8*)(Q + g);
        k8[r] = *(const bf16x8*)(K + g);
        v8[r] = *(const bf16x8*)(V + g);
    }

    // gates: prefix-sum of log(alpha) over the chunk (wave 0, coalesced)
    if (tid < 64) {
        const int t = tid;
        const size_t gaT = (size_t)h * NROWS + b * T_LEN + t0 + t;
        const float a  = AlphaT[gaT];
        const float bt = BetaT[gaT];
        float xx = logf(a);
#pragma unroll
        for (int off = 1; off < 64; off <<= 1) {
            const float y = __shfl_up(xx, off, 64);
            if (t >= off) xx += y;
        }
        const float la63 = __shfl(xx, 63, 64);
        sla[t] = xx;
        sb[t]  = bt;
        swd[t] = bt * __expf(la63 - xx);
        ExpT[gaT] = __expf(xx);
        if (t == 63) Dec[(size_t)(b * NH + h) * NCH + c] = __expf(la63);
    }
    __syncthreads();

    // stage to LDS: normalize k rows (8 lanes per row -> 3 shfl_xor)
#pragma unroll
    for (int r = 0; r < 2; r++) {
        const int row = srow + 32 * r;
        float kf[8];
        float ss = 0.f;
#pragma unroll
        for (int j = 0; j < 8; j++) { kf[j] = (float)k8[r][j]; ss += kf[j] * kf[j]; }
        ss += __shfl_xor(ss, 1, 64);
        ss += __shfl_xor(ss, 2, 64);
        ss += __shfl_xor(ss, 4, 64);
        const float scale = 1.f / fmaxf(sqrtf(ss), 1e-12f);
        const float w = swd[row];
        bf16x8 kn8;
#pragma unroll
        for (int j = 0; j < 8; j++) {
            const float kn = kf[j] * scale;
            kn8[j] = (__bf16)kn;
            KTs[swz(scol + j, row)] = (__bf16)(w * kn);
            VTb[swz(scol + j, row)] = v8[r][j];
        }
        *(bf16x8*)&Qb[swz(row, scol)] = q8[r];
        *(bf16x8*)&Kb[swz(row, scol)] = kn8;
    }
    __syncthreads();

    const int quad = lane >> 4;
    const int frow = lane & 15;
    const int tw = wid * 16;   // this wave's 16-row output stripe

    // ---- G = Q K^T ----
    f32x4 accG[4];
#pragma unroll
    for (int i = 0; i < 4; i++) accG[i] = (f32x4)0.f;
#pragma unroll
    for (int ks = 0; ks < 2; ks++) {
        const int ko = quad * 8 + 32 * ks;
        const bf16x8 aq = *(const bf16x8*)&Qb[swz(tw + frow, ko)];
#pragma unroll
        for (int st = 0; st < 4; st++) {
            const bf16x8 bk = *(const bf16x8*)&Kb[swz(st * 16 + frow, ko)];
            accG[st] = __builtin_amdgcn_mfma_f32_16x16x32_bf16(aq, bk, accG[st], 0, 0, 0);
        }
    }
    // ---- mask -> Ab (C layout: row=quad*4+r, col=frow) ----
#pragma unroll
    for (int st = 0; st < 4; st++) {
#pragma unroll
        for (int r = 0; r < 4; r++) {
            const int t = tw + quad * 4 + r;
            const int s = st * 16 + frow;
            const float av = (s <= t) ? __expf(sla[t] - sla[s]) * sb[s] * accG[st][r] : 0.f;
            Ab[swz(t, s)] = (__bf16)av;
        }
    }
    __syncthreads();

    // ---- Y_intra = A V  and  dS^T = KTs * VT^T (A/B swapped -> [j][i]) ----
    f32x4 accY[4], accD[4];
#pragma unroll
    for (int i = 0; i < 4; i++) { accY[i] = (f32x4)0.f; accD[i] = (f32x4)0.f; }
#pragma unroll
    for (int ks = 0; ks < 2; ks++) {
        const int ko = quad * 8 + 32 * ks;
        const bf16x8 aA = *(const bf16x8*)&Ab[swz(tw + frow, ko)];
        const bf16x8 aK = *(const bf16x8*)&KTs[swz(tw + frow, ko)];
#pragma unroll
        for (int jt = 0; jt < 4; jt++) {
            const bf16x8 bv = *(const bf16x8*)&VTb[swz(jt * 16 + frow, ko)];
            accY[jt] = __builtin_amdgcn_mfma_f32_16x16x32_bf16(aA, bv, accY[jt], 0, 0, 0);
            accD[jt] = __builtin_amdgcn_mfma_f32_16x16x32_bf16(aK, bv, accD[jt], 0, 0, 0);
        }
    }
    // write Y_intra (bf16) over V, dS^T (fp32) to DS (row slot = j, col = i)
#pragma unroll
    for (int jt = 0; jt < 4; jt++) {
#pragma unroll
        for (int r = 0; r < 4; r++) {
            const int row = tw + quad * 4 + r;
            const size_t g = rowbase + (size_t)row * INNER + jt * 16 + frow;
            V[g]  = (__bf16)accY[jt][r];
            DS[g] = accD[jt][r];
        }
    }
}

// ---------------------------------------------------------------------------
// Fused inter-chunk scan + Y_inter (in-register state, replaces 2 kernels).
// ---------------------------------------------------------------------------
__global__ __launch_bounds__(256) void state_y(const __bf16* __restrict__ Q,
                                               const float* __restrict__ DS,
                                               const float* __restrict__ Dec,
                                               const float* __restrict__ ExpT,
                                               const float* __restrict__ state_in,
                                               float* __restrict__ state_out,
                                               __bf16* __restrict__ Yb) {
    const int blk = blockIdx.x;
    const int b = blk >> 6, h = (blk >> 2) & 15, iq = blk & 3;
    const int tid = threadIdx.x;
    const int wid = tid >> 6, lane = tid & 63;
    const int frow = lane & 15, quad = lane >> 4;
    const int tw = wid * 16;
    const int i = iq * 16 + frow;          // this lane's state column

    // init state slice: S[ks][e] = state[b,h,i, j=32ks+quad*8+e]
    float S[2][8];
    {
        const float* st = state_in + ((size_t)((b * NH + h) * DH) + i) * DH;
#pragma unroll
        for (int ks = 0; ks < 2; ks++) {
            const int j0 = 32 * ks + quad * 8;
            const float4 a = *(const float4*)(st + j0);
            const float4 d = *(const float4*)(st + j0 + 4);
            S[ks][0] = a.x; S[ks][1] = a.y; S[ks][2] = a.z; S[ks][3] = a.w;
            S[ks][4] = d.x; S[ks][5] = d.y; S[ks][6] = d.z; S[ks][7] = d.w;
        }
    }

    const size_t bh = (size_t)(b * NH + h);
#pragma unroll 2
    for (int c = 0; c < NCH; c++) {
        const int t0 = c * CH;
        const size_t rowbase = ((size_t)(b * T_LEN + t0) * NH + h) * DH;
        const float decay = Dec[bh * NCH + c];

        // Q A-fragments first (MFMA's only memory dependency)
        const bf16x8 aq0 = *(const bf16x8*)(Q + rowbase + (size_t)(tw + frow) * INNER + quad * 8);
        const bf16x8 aq1 = *(const bf16x8*)(Q + rowbase + (size_t)(tw + frow) * INNER + 32 + quad * 8);

        // dS^T loads (scan-independent; overlap MFMA)
        float ds[2][8];
#pragma unroll
        for (int ks = 0; ks < 2; ks++) {
            const int j0 = 32 * ks + quad * 8;
#pragma unroll
            for (int e = 0; e < 8; e++)
                ds[ks][e] = DS[rowbase + (size_t)(j0 + e) * INNER + i];
        }

        // B-fragments from PRE-update state
        bf16x8 bs0, bs1;
#pragma unroll
        for (int e = 0; e < 8; e++) { bs0[e] = (__bf16)S[0][e]; bs1[e] = (__bf16)S[1][e]; }

        f32x4 acc = (f32x4)0.f;
        acc = __builtin_amdgcn_mfma_f32_16x16x32_bf16(aq0, bs0, acc, 0, 0, 0);
        acc = __builtin_amdgcn_mfma_f32_16x16x32_bf16(aq1, bs1, acc, 0, 0, 0);

        // state scan update (elementwise)
#pragma unroll
        for (int ks = 0; ks < 2; ks++)
#pragma unroll
            for (int e = 0; e < 8; e++)
                S[ks][e] = decay * S[ks][e] + ds[ks][e];

        // Yb RMW: C layout row=quad*4+r (t-sub), col=frow (i)
#pragma unroll
        for (int r = 0; r < 4; r++) {
            const int t = tw + quad * 4 + r;
            const float ee = ExpT[(size_t)h * NROWS + b * T_LEN + t0 + t];
            __bf16* yp = Yb + rowbase + (size_t)t * INNER + i;
            *yp = (__bf16)(ee * acc[r] + (float)*yp);
        }
    }

    // final state (fp32, [i][j]) -- j contiguous per lane -> float4
    float* so = state_out + ((size_t)((b * NH + h) * DH) + i) * DH;
#pragma unroll
    for (int ks = 0; ks < 2; ks++) {
        const int j0 = 32 * ks + quad * 8;
        const float4 v0 = {S[ks][0], S[ks][1], S[ks][2], S[ks][3]};
        const float4 v1 = {S[ks][4], S[ks][5], S[ks][6], S[ks][7]};
        *(float4*)(so + j0)     = v0;
        *(float4*)(so + j0 + 4) = v1;
    }
}

// ---------------------------------------------------------------------------
extern "C" void kernel_launch(void* const* d_in, const int* in_sizes, int n_in,
                              void* d_out, int out_size, void* d_ws, size_t ws_size,
                              hipStream_t stream) {
    const float* x     = (const float*)d_in[0];
    const float* state = (const float*)d_in[1];
    const float* Wq    = (const float*)d_in[2];
    const float* Wk    = (const float*)d_in[3];
    const float* Wv    = (const float*)d_in[4];
    const float* Wa    = (const float*)d_in[5];
    const float* ba    = (const float*)d_in[6];
    const float* Wb    = (const float*)d_in[7];
    const float* bb    = (const float*)d_in[8];
    const float* Wo    = (const float*)d_in[9];

    __bf16* Qb    = (__bf16*)d_ws;               // NQ bf16 (raw q, preserved)
    __bf16* Kbf   = Qb + (size_t)NQ;             // NQ bf16 (raw k)
    __bf16* Vbf   = Kbf + (size_t)NQ;            // NQ bf16 (v -> Y_intra -> Y)
    float*  DS    = (float*)(Vbf + (size_t)NQ);  // NQ fp32 (dS^T)
    float*  AlphaT= DS + (size_t)NQ;             // [NH][NROWS]
    float*  BetaT = AlphaT + (size_t)NROWS * NH;
    float*  ExpT  = BetaT + (size_t)NROWS * NH;  // [NH][NROWS] exp(la_t)
    float*  Dec   = ExpT + (size_t)NROWS * NH;   // per-chunk decay
    __bf16* xb    = (__bf16*)(Dec + (size_t)B_SZ * NH * NCH);
    __bf16* WqT   = xb + (size_t)NQ;             // [WqT|WkT|WvT] contiguous
    __bf16* WkT   = WqT + (size_t)DM * INNER;
    __bf16* WvT   = WkT + (size_t)DM * INNER;
    __bf16* WoT   = WvT + (size_t)DM * INNER;

    float* out  = (float*)d_out;                // (B,T,DM)
    float* Sout = out + (size_t)NQ;             // (B,H,D,D)

    // 0) weights cast+transpose
    wt_cast_transpose<<<dim3(16, 16, 4), 256, 0, stream>>>(Wq, Wk, Wv, Wo,
                                                           WqT, WkT, WvT, WoT);
    // 1) fused gates (MFMA) + x->bf16 cast
    gates_fused<<<NROWS / 64, 256, 0, stream>>>(x, Wa, ba, Wb, bb,
                                                AlphaT, BetaT, xb);
    // 2) Q/K/V projections: v2 pipeline, 768 blocks = 3 clean rounds
    qkv_gemm_v2<<<768, 512, 0, stream>>>(xb, WqT, Qb);
    // 3) intra-chunk MFMA (+fused knorm): Y_intra -> Vbf, dS^T -> DS
    chunk_ds<<<B_SZ * NH * NCH, 256, 0, stream>>>(Qb, Kbf, Vbf, AlphaT, BetaT,
                                                  Dec, DS, ExpT);
    // 4) fused inter-chunk scan + Y_inter finalize (in-register state)
    state_y<<<B_SZ * NH * 4, 256, 0, stream>>>(Qb, DS, Dec, ExpT, state,
                                               Sout, Vbf);
    // 5) output projection: v2 pipeline, 256 blocks = 1 clean round
    out_gemm_v2<<<256, 512, 0, stream>>>(Vbf, WoT, out);
}

// Round 6
// 256.182 us; speedup vs baseline: 1.0594x; 1.0594x over previous
//
#include <hip/hip_runtime.h>
#include <hip/hip_bf16.h>
#include <math.h>

// Problem constants
#define B_SZ   4
#define T_LEN  2048
#define DM     1024
#define NH     16
#define DH     64
#define INNER  1024          // NH*DH
#define NROWS  (B_SZ*T_LEN)  // 8192
#define NQ     (NROWS*INNER) // elements per Q/K/V/Y buffer
#define CH     64            // chunk length
#define NCH    (T_LEN/CH)    // 32 chunks

typedef __bf16 bf16x8 __attribute__((ext_vector_type(8)));
typedef __bf16 bf16x4 __attribute__((ext_vector_type(4)));
typedef float  f32x4  __attribute__((ext_vector_type(4)));
typedef __attribute__((address_space(3))) void*       lds_vp;
typedef const __attribute__((address_space(1))) void* gbl_vp;

// Swizzled index into a 64x64 bf16 LDS tile: 8-elem blocks rotated by row>>2.
__device__ __forceinline__ int swz(int row, int col) {
    return (row << 6) + ((((col >> 3) + (row >> 2)) & 7) << 3) + (col & 7);
}

// ---------------------------------------------------------------------------
// Weight transpose + cast: W (K x N fp32, row-major) -> WT (N x K bf16).
// ---------------------------------------------------------------------------
__global__ __launch_bounds__(256) void wt_cast_transpose(const float* __restrict__ Wq,
                                                         const float* __restrict__ Wk,
                                                         const float* __restrict__ Wv,
                                                         const float* __restrict__ Wo,
                                                         __bf16* __restrict__ WqT,
                                                         __bf16* __restrict__ WkT,
                                                         __bf16* __restrict__ WvT,
                                                         __bf16* __restrict__ WoT) {
    __shared__ float tile[64][65];
    const float* W;
    __bf16* WT;
    if      (blockIdx.z == 0) { W = Wq; WT = WqT; }
    else if (blockIdx.z == 1) { W = Wk; WT = WkT; }
    else if (blockIdx.z == 2) { W = Wv; WT = WvT; }
    else                      { W = Wo; WT = WoT; }

    const int k0 = blockIdx.y * 64, n0 = blockIdx.x * 64;
    const int tr  = threadIdx.x >> 4;        // 0..15
    const int tc4 = (threadIdx.x & 15) * 4;  // 0..60

#pragma unroll
    for (int r = 0; r < 4; r++) {
        const int k = tr + 16 * r;
        const float4 v = *(const float4*)(W + (size_t)(k0 + k) * DM + n0 + tc4);
        tile[k][tc4 + 0] = v.x;
        tile[k][tc4 + 1] = v.y;
        tile[k][tc4 + 2] = v.z;
        tile[k][tc4 + 3] = v.w;
    }
    __syncthreads();
#pragma unroll
    for (int r = 0; r < 4; r++) {
        const int n = tr + 16 * r;
        bf16x4 o;
#pragma unroll
        for (int j = 0; j < 4; j++) o[j] = (__bf16)tile[tc4 + j][n];
        *(bf16x4*)(WT + (size_t)(n0 + n) * DM + k0 + tc4) = o;
    }
}

// ---------------------------------------------------------------------------
// 3-stage pipelined bf16 MFMA GEMM, fragment-reuse geometry (r3 verified:
// 59.1us qkv, 0 bank conflicts, MfmaUtil 35, 2 blocks/CU).
// ---------------------------------------------------------------------------
#define STAGE_STRIDE 24576          // A 16384 + B 8192 bytes
#define B_BASE 16384

template <typename CT>
__device__ __forceinline__ void gemm_pipe_body(const __bf16* __restrict__ A,
                                               const __bf16* __restrict__ BT,
                                               CT* __restrict__ C,
                                               int m0, int n0bt, int n0c) {
    __shared__ __align__(16) char lds[3 * STAGE_STRIDE];

    const int tid  = threadIdx.x;
    const int wid  = tid >> 6;       // 0..3
    const int lane = tid & 63;
    const int wm = wid >> 1;         // 0..1 : 128-row stripe
    const int wn = wid & 1;          // 0..1 : 64-col stripe
    const int frow = lane & 15, quad = lane >> 4;

    // swizzled ds_read byte offsets within one stage (loop-invariant)
    int offA[8], offB[4];
#pragma unroll
    for (int i = 0; i < 8; ++i) {
        const int ra = wm * 128 + i * 16 + frow;
        offA[i] = ra * 64 + ((quad ^ ((ra >> 1) & 3)) << 4);
    }
#pragma unroll
    for (int j = 0; j < 4; ++j) {
        const int rb = wn * 64 + j * 16 + frow;
        offB[j] = B_BASE + rb * 64 + ((quad ^ ((rb >> 1) & 3)) << 4);
    }

    // staging: per-lane pre-swizzled global source (16 rows x 64B per instr)
    const int lr = lane >> 2;                                  // row in region
    const int cs = ((lane & 3) ^ ((lane >> 3) & 3)) << 3;      // elem col (swz)
    const __bf16* gA[4];
#pragma unroll
    for (int q = 0; q < 4; ++q)
        gA[q] = A + (size_t)(m0 + wid * 64 + q * 16 + lr) * 1024 + cs;
    const __bf16* gB[2];
#pragma unroll
    for (int q = 0; q < 2; ++q)
        gB[q] = BT + (size_t)(n0bt + wid * 32 + q * 16 + lr) * 1024 + cs;

    // one staging group: 6 global_load_lds per wave (4 A + 2 B regions)
#define STG(t_, b_) do {                                                           \
        _Pragma("unroll")                                                          \
        for (int q_ = 0; q_ < 4; ++q_)                                             \
            __builtin_amdgcn_global_load_lds((gbl_vp)(gA[q_] + (size_t)(t_) * 32), \
                (lds_vp)(lds + (b_) * STAGE_STRIDE + (wid * 64 + q_ * 16) * 64),   \
                16, 0, 0);                                                         \
        _Pragma("unroll")                                                          \
        for (int q_ = 0; q_ < 2; ++q_)                                             \
            __builtin_amdgcn_global_load_lds((gbl_vp)(gB[q_] + (size_t)(t_) * 32), \
                (lds_vp)(lds + (b_) * STAGE_STRIDE + B_BASE + (wid * 32 + q_ * 16) * 64), \
                16, 0, 0);                                                         \
    } while (0)

#define VM6 asm volatile("s_waitcnt vmcnt(6)" ::: "memory")
#define VM0 asm volatile("s_waitcnt vmcnt(0)" ::: "memory")

    f32x4 acc[8][4];
#pragma unroll
    for (int i = 0; i < 8; i++)
#pragma unroll
        for (int j = 0; j < 4; j++) acc[i][j] = (f32x4)0.f;

    // prologue: stage K-tiles 0,1 (12 loads/wave in flight); wait tile 0
    STG(0, 0); STG(1, 1);
    VM6;
    asm volatile("s_barrier" ::: "memory");

    // one phase: ds_read frags || prefetch issue -> bar -> lgkm0 -> MFMA -> vm -> bar
#define PH(b_, STG_STMT, VM_STMT)                                                  \
    {                                                                              \
        const char* Sb_ = lds + (b_) * STAGE_STRIDE;                               \
        bf16x8 af_[8], bfr_[4];                                                    \
        _Pragma("unroll")                                                          \
        for (int i_ = 0; i_ < 8; ++i_) af_[i_]  = *(const bf16x8*)(Sb_ + offA[i_]);\
        _Pragma("unroll")                                                          \
        for (int j_ = 0; j_ < 4; ++j_) bfr_[j_] = *(const bf16x8*)(Sb_ + offB[j_]);\
        STG_STMT;                                                                  \
        asm volatile("s_barrier" ::: "memory");                                    \
        asm volatile("s_waitcnt lgkmcnt(0)" ::: "memory");                         \
        __builtin_amdgcn_sched_barrier(0);                                         \
        __builtin_amdgcn_s_setprio(1);                                             \
        _Pragma("unroll")                                                          \
        for (int mi_ = 0; mi_ < 8; ++mi_)                                          \
            _Pragma("unroll")                                                      \
            for (int nj_ = 0; nj_ < 4; ++nj_)                                      \
                acc[mi_][nj_] = __builtin_amdgcn_mfma_f32_16x16x32_bf16(           \
                    af_[mi_], bfr_[nj_], acc[mi_][nj_], 0, 0, 0);                  \
        __builtin_amdgcn_s_setprio(0);                                             \
        VM_STMT;                                                                   \
        asm volatile("s_barrier" ::: "memory");                                    \
    }

    // main loop: phases 0..29 (buffer residues static via unroll-by-3);
    // phase p issues the staging group for K-tile p+2.
    for (int u = 0; u < 10; ++u) {
        const int p = 3 * u;
        PH(0, STG(p + 2, 2), VM6);
        PH(1, STG(p + 3, 0), VM6);
        PH(2, STG(p + 4, 1), VM6);
    }
    // phases 30,31: drain
    PH(0, , VM0);
    PH(1, , );

#undef PH
#undef STG
#undef VM6
#undef VM0

    // epilogue: C-write (same fragment mapping as verified base kernel)
    const int cr = quad * 4, cc = frow;
#pragma unroll
    for (int mi = 0; mi < 8; ++mi) {
#pragma unroll
        for (int nj = 0; nj < 4; ++nj) {
            CT* Cp = C + (size_t)(m0 + wm * 128 + mi * 16 + cr) * 1024
                       + n0c + wn * 64 + nj * 16 + cc;
#pragma unroll
            for (int r = 0; r < 4; r++) Cp[(size_t)r * 1024] = (CT)acc[mi][nj][r];
        }
    }
}

// Fused QKV: BTall = [WqT|WkT|WvT] as [3072][1024]; QKV = [Q|K|V] contiguous.
// 768 blocks = 32 m-tiles x 24 n-tiles; 2 blocks/CU resident.
// XCD swizzle (T1, bijective: 768 % 8 == 0).
__global__ __launch_bounds__(256, 2) void qkv_gemm_8ph(const __bf16* __restrict__ xb,
                                                       const __bf16* __restrict__ BTall,
                                                       __bf16* __restrict__ QKV) {
    const int id = blockIdx.x;
    const int wg = (id & 7) * 96 + (id >> 3);
    const int mt = wg / 24, nt = wg % 24;
    const int mat = nt >> 3;
    gemm_pipe_body<__bf16>(xb, BTall, QKV + (size_t)mat * NQ,
                           mt * 256, nt * 128, (nt & 7) * 128);
}

// Output projection: 256 blocks (32 m x 8 n), all co-resident.
__global__ __launch_bounds__(256, 2) void out_gemm_8ph(const __bf16* __restrict__ Yb,
                                                       const __bf16* __restrict__ WoT,
                                                       float* __restrict__ Cout) {
    const int id = blockIdx.x;
    const int wg = (id & 7) * 32 + (id >> 3);
    const int mt = wg >> 3, nt = wg & 7;
    gemm_pipe_body<float>(Yb, WoT, Cout, mt * 256, nt * 128, nt * 128);
}

// ---------------------------------------------------------------------------
// Fused gates + x cast (MFMA).  NOW 256 blocks x 256 thr; block = 32 rows
// (was 128 blocks / 64 rows -> HALF the GPU idle for an HBM-bound pass).
// 4 waves: (row-half rh = wid>>1) x (gate-col-half ct = wid&1); K=64/iter.
// ---------------------------------------------------------------------------
#define WGS  1032  // lWg row stride (bf16): 516 dw, 4-dw bank rotation
#define LAS2 72    // lA row stride (bf16): 36 dw -> 4-bank row rotation (2-way free)
__global__ __launch_bounds__(256) void gates_fused(const float* __restrict__ x,
                                                   const float* __restrict__ Wa,
                                                   const float* __restrict__ ba,
                                                   const float* __restrict__ Wb,
                                                   const float* __restrict__ bb,
                                                   float* __restrict__ AlphaT,
                                                   float* __restrict__ BetaT,
                                                   __bf16* __restrict__ xb) {
    __shared__ __align__(16) __bf16 lWg[32 * WGS];
    __shared__ __align__(16) __bf16 lA[32 * LAS2];

    const int tid = threadIdx.x;
    const int wid = tid >> 6, lane = tid & 63;
    const int quad = lane >> 4, frow = lane & 15;
    const int rh = wid >> 1, ct = wid & 1;
    const int m0 = blockIdx.x * 32;

    // ---- stage W^T (bf16) into LDS ----
    {
        const int kbase = tid * 4;
#pragma unroll
        for (int j = 0; j < 4; j++) {
            const int k = kbase + j;
            const float4* war = (const float4*)(Wa + (size_t)k * NH);
            const float4* wbr = (const float4*)(Wb + (size_t)k * NH);
#pragma unroll
            for (int q = 0; q < 4; q++) {
                const float4 a = war[q], bq = wbr[q];
                lWg[(q * 4 + 0) * WGS + k] = (__bf16)a.x;
                lWg[(q * 4 + 1) * WGS + k] = (__bf16)a.y;
                lWg[(q * 4 + 2) * WGS + k] = (__bf16)a.z;
                lWg[(q * 4 + 3) * WGS + k] = (__bf16)a.w;
                lWg[(16 + q * 4 + 0) * WGS + k] = (__bf16)bq.x;
                lWg[(16 + q * 4 + 1) * WGS + k] = (__bf16)bq.y;
                lWg[(16 + q * 4 + 2) * WGS + k] = (__bf16)bq.z;
                lWg[(16 + q * 4 + 3) * WGS + k] = (__bf16)bq.w;
            }
        }
    }
    const float bias = (ct == 0) ? ba[frow] : bb[frow];

    // ---- pipelined K loop: 16 iters of K=64 ----
    const int rrow = tid >> 3;          // 0..31
    const int rk   = (tid & 7) * 8;     // 0..56
    const float* xrow = x + (size_t)(m0 + rrow) * DM + rk;
    float4 c0 = *(const float4*)(xrow + 0);
    float4 c1 = *(const float4*)(xrow + 4);

    f32x4 acc = (f32x4)0.f;

    for (int k0 = 0; k0 < DM; k0 += 64) {
        __syncthreads();   // prev iter's lA reads done (also covers lWg stage)
        bf16x8 xv;
        xv[0] = (__bf16)c0.x; xv[1] = (__bf16)c0.y; xv[2] = (__bf16)c0.z; xv[3] = (__bf16)c0.w;
        xv[4] = (__bf16)c1.x; xv[5] = (__bf16)c1.y; xv[6] = (__bf16)c1.z; xv[7] = (__bf16)c1.w;
        *(bf16x8*)&lA[rrow * LAS2 + rk] = xv;
        *(bf16x8*)(xb + (size_t)(m0 + rrow) * DM + k0 + rk) = xv;
        if (k0 + 64 < DM) {
            c0 = *(const float4*)(xrow + k0 + 64);
            c1 = *(const float4*)(xrow + k0 + 68);
        }
        __syncthreads();
#pragma unroll
        for (int ks = 0; ks < 2; ks++) {
            const bf16x8 af = *(const bf16x8*)&lA[(rh * 16 + frow) * LAS2 + ks * 32 + quad * 8];
            const bf16x8 bf = *(const bf16x8*)&lWg[(ct * 16 + frow) * WGS + k0 + ks * 32 + quad * 8];
            acc = __builtin_amdgcn_mfma_f32_16x16x32_bf16(af, bf, acc, 0, 0, 0);
        }
    }

    // ---- sigmoid epilogue, transposed store ----
    float* dst = (ct == 0) ? AlphaT : BetaT;
#pragma unroll
    for (int r = 0; r < 4; r++) {
        const int row = m0 + rh * 16 + quad * 4 + r;
        const float s = acc[r] + bias;
        dst[(size_t)frow * NROWS + row] = 1.f / (1.f + __expf(-s));
    }
}

// ---------------------------------------------------------------------------
// Pass A (MFMA, bf16 I/O): per (b,h,c), 256 threads = 4 waves.
//   G = Q K^T ; A = mask*exp(la_t-la_s)*b_s*G ; Y_intra = A V -> V (bf16)
//   dS^T[j][i] -> DS (fp32, transposed for state_y).
// ---------------------------------------------------------------------------
__global__ __launch_bounds__(256) void chunk_ds(const __bf16* __restrict__ Q,
                                                const __bf16* __restrict__ K,
                                                __bf16* __restrict__ V,
                                                const float* __restrict__ AlphaT,
                                                const float* __restrict__ BetaT,
                                                float* __restrict__ Dec,
                                                float* __restrict__ DS,
                                                float* __restrict__ ExpT) {
    __shared__ __align__(16) __bf16 Qb[64 * 64];
    __shared__ __align__(16) __bf16 Kb[64 * 64];
    __shared__ __align__(16) __bf16 KTs[64 * 64];  // [j][s] = swd_s * kn[s][j]
    __shared__ __align__(16) __bf16 VTb[64 * 64];  // [i][s] = V[s][i]
    __shared__ __align__(16) __bf16 Ab[64 * 64];   // [t][s]
    __shared__ float sla[64], sb[64], swd[64];

    const int blk = blockIdx.x;
    const int c = blk & 31, h = (blk >> 5) & 15, b = blk >> 9;
    const int t0 = c * CH;
    const int tid = threadIdx.x;
    const int wid = tid >> 6, lane = tid & 63;
    const size_t rowbase = ((size_t)(b * T_LEN + t0) * NH + h) * DH;

    // prefetch (16B bf16x8 per matrix per round)
    const int srow = tid >> 3;          // 0..31
    const int scol = (tid & 7) * 8;     // 0..56
    bf16x8 q8[2], k8[2], v8[2];
#pragma unroll
    for (int r = 0; r < 2; r++) {
        const size_t g = rowbase + (size_t)(srow + 32 * r) * INNER + scol;
        q8[r] = *(const bf16x8*)(Q + g);
        k8[r] = *(const bf16x8*)(K + g);
        v8[r] = *(const bf16x8*)(V + g);
    }

    // gates: prefix-sum of log(alpha) over the chunk (wave 0, coalesced)
    if (tid < 64) {
        const int t = tid;
        const size_t gaT = (size_t)h * NROWS + b * T_LEN + t0 + t;
        const float a  = AlphaT[gaT];
        const float bt = BetaT[gaT];
        float xx = logf(a);
#pragma unroll
        for (int off = 1; off < 64; off <<= 1) {
            const float y = __shfl_up(xx, off, 64);
            if (t >= off) xx += y;
        }
        const float la63 = __shfl(xx, 63, 64);
        sla[t] = xx;
        sb[t]  = bt;
        swd[t] = bt * __expf(la63 - xx);
        ExpT[gaT] = __expf(xx);
        if (t == 63) Dec[(size_t)(b * NH + h) * NCH + c] = __expf(la63);
    }
    __syncthreads();

    // stage to LDS: normalize k rows (8 lanes per row -> 3 shfl_xor)
#pragma unroll
    for (int r = 0; r < 2; r++) {
        const int row = srow + 32 * r;
        float kf[8];
        float ss = 0.f;
#pragma unroll
        for (int j = 0; j < 8; j++) { kf[j] = (float)k8[r][j]; ss += kf[j] * kf[j]; }
        ss += __shfl_xor(ss, 1, 64);
        ss += __shfl_xor(ss, 2, 64);
        ss += __shfl_xor(ss, 4, 64);
        const float scale = 1.f / fmaxf(sqrtf(ss), 1e-12f);
        const float w = swd[row];
        bf16x8 kn8;
#pragma unroll
        for (int j = 0; j < 8; j++) {
            const float kn = kf[j] * scale;
            kn8[j] = (__bf16)kn;
            KTs[swz(scol + j, row)] = (__bf16)(w * kn);
            VTb[swz(scol + j, row)] = v8[r][j];
        }
        *(bf16x8*)&Qb[swz(row, scol)] = q8[r];
        *(bf16x8*)&Kb[swz(row, scol)] = kn8;
    }
    __syncthreads();

    const int quad = lane >> 4;
    const int frow = lane & 15;
    const int tw = wid * 16;   // this wave's 16-row output stripe

    // ---- G = Q K^T ----
    f32x4 accG[4];
#pragma unroll
    for (int i = 0; i < 4; i++) accG[i] = (f32x4)0.f;
#pragma unroll
    for (int ks = 0; ks < 2; ks++) {
        const int ko = quad * 8 + 32 * ks;
        const bf16x8 aq = *(const bf16x8*)&Qb[swz(tw + frow, ko)];
#pragma unroll
        for (int st = 0; st < 4; st++) {
            const bf16x8 bk = *(const bf16x8*)&Kb[swz(st * 16 + frow, ko)];
            accG[st] = __builtin_amdgcn_mfma_f32_16x16x32_bf16(aq, bk, accG[st], 0, 0, 0);
        }
    }
    // ---- mask -> Ab (C layout: row=quad*4+r, col=frow) ----
#pragma unroll
    for (int st = 0; st < 4; st++) {
#pragma unroll
        for (int r = 0; r < 4; r++) {
            const int t = tw + quad * 4 + r;
            const int s = st * 16 + frow;
            const float av = (s <= t) ? __expf(sla[t] - sla[s]) * sb[s] * accG[st][r] : 0.f;
            Ab[swz(t, s)] = (__bf16)av;
        }
    }
    __syncthreads();

    // ---- Y_intra = A V  and  dS^T = KTs * VT^T (A/B swapped -> [j][i]) ----
    f32x4 accY[4], accD[4];
#pragma unroll
    for (int i = 0; i < 4; i++) { accY[i] = (f32x4)0.f; accD[i] = (f32x4)0.f; }
#pragma unroll
    for (int ks = 0; ks < 2; ks++) {
        const int ko = quad * 8 + 32 * ks;
        const bf16x8 aA = *(const bf16x8*)&Ab[swz(tw + frow, ko)];
        const bf16x8 aK = *(const bf16x8*)&KTs[swz(tw + frow, ko)];
#pragma unroll
        for (int jt = 0; jt < 4; jt++) {
            const bf16x8 bv = *(const bf16x8*)&VTb[swz(jt * 16 + frow, ko)];
            accY[jt] = __builtin_amdgcn_mfma_f32_16x16x32_bf16(aA, bv, accY[jt], 0, 0, 0);
            accD[jt] = __builtin_amdgcn_mfma_f32_16x16x32_bf16(aK, bv, accD[jt], 0, 0, 0);
        }
    }
    // write Y_intra (bf16) over V, dS^T (fp32) to DS (row slot = j, col = i)
#pragma unroll
    for (int jt = 0; jt < 4; jt++) {
#pragma unroll
        for (int r = 0; r < 4; r++) {
            const int row = tw + quad * 4 + r;
            const size_t g = rowbase + (size_t)row * INNER + jt * 16 + frow;
            V[g]  = (__bf16)accY[jt][r];
            DS[g] = accD[jt][r];
        }
    }
}

// ---------------------------------------------------------------------------
// Fused inter-chunk scan + Y_inter (in-register state, replaces 2 kernels).
// ---------------------------------------------------------------------------
__global__ __launch_bounds__(256) void state_y(const __bf16* __restrict__ Q,
                                               const float* __restrict__ DS,
                                               const float* __restrict__ Dec,
                                               const float* __restrict__ ExpT,
                                               const float* __restrict__ state_in,
                                               float* __restrict__ state_out,
                                               __bf16* __restrict__ Yb) {
    const int blk = blockIdx.x;
    const int b = blk >> 6, h = (blk >> 2) & 15, iq = blk & 3;
    const int tid = threadIdx.x;
    const int wid = tid >> 6, lane = tid & 63;
    const int frow = lane & 15, quad = lane >> 4;
    const int tw = wid * 16;
    const int i = iq * 16 + frow;          // this lane's state column

    // init state slice: S[ks][e] = state[b,h,i, j=32ks+quad*8+e]
    float S[2][8];
    {
        const float* st = state_in + ((size_t)((b * NH + h) * DH) + i) * DH;
#pragma unroll
        for (int ks = 0; ks < 2; ks++) {
            const int j0 = 32 * ks + quad * 8;
            const float4 a = *(const float4*)(st + j0);
            const float4 d = *(const float4*)(st + j0 + 4);
            S[ks][0] = a.x; S[ks][1] = a.y; S[ks][2] = a.z; S[ks][3] = a.w;
            S[ks][4] = d.x; S[ks][5] = d.y; S[ks][6] = d.z; S[ks][7] = d.w;
        }
    }

    const size_t bh = (size_t)(b * NH + h);
#pragma unroll 2
    for (int c = 0; c < NCH; c++) {
        const int t0 = c * CH;
        const size_t rowbase = ((size_t)(b * T_LEN + t0) * NH + h) * DH;
        const float decay = Dec[bh * NCH + c];

        // Q A-fragments first (MFMA's only memory dependency)
        const bf16x8 aq0 = *(const bf16x8*)(Q + rowbase + (size_t)(tw + frow) * INNER + quad * 8);
        const bf16x8 aq1 = *(const bf16x8*)(Q + rowbase + (size_t)(tw + frow) * INNER + 32 + quad * 8);

        // dS^T loads (scan-independent; overlap MFMA)
        float ds[2][8];
#pragma unroll
        for (int ks = 0; ks < 2; ks++) {
            const int j0 = 32 * ks + quad * 8;
#pragma unroll
            for (int e = 0; e < 8; e++)
                ds[ks][e] = DS[rowbase + (size_t)(j0 + e) * INNER + i];
        }

        // B-fragments from PRE-update state
        bf16x8 bs0, bs1;
#pragma unroll
        for (int e = 0; e < 8; e++) { bs0[e] = (__bf16)S[0][e]; bs1[e] = (__bf16)S[1][e]; }

        f32x4 acc = (f32x4)0.f;
        acc = __builtin_amdgcn_mfma_f32_16x16x32_bf16(aq0, bs0, acc, 0, 0, 0);
        acc = __builtin_amdgcn_mfma_f32_16x16x32_bf16(aq1, bs1, acc, 0, 0, 0);

        // state scan update (elementwise)
#pragma unroll
        for (int ks = 0; ks < 2; ks++)
#pragma unroll
            for (int e = 0; e < 8; e++)
                S[ks][e] = decay * S[ks][e] + ds[ks][e];

        // Yb RMW: C layout row=quad*4+r (t-sub), col=frow (i)
#pragma unroll
        for (int r = 0; r < 4; r++) {
            const int t = tw + quad * 4 + r;
            const float ee = ExpT[(size_t)h * NROWS + b * T_LEN + t0 + t];
            __bf16* yp = Yb + rowbase + (size_t)t * INNER + i;
            *yp = (__bf16)(ee * acc[r] + (float)*yp);
        }
    }

    // final state (fp32, [i][j]) -- j contiguous per lane -> float4
    float* so = state_out + ((size_t)((b * NH + h) * DH) + i) * DH;
#pragma unroll
    for (int ks = 0; ks < 2; ks++) {
        const int j0 = 32 * ks + quad * 8;
        const float4 v0 = {S[ks][0], S[ks][1], S[ks][2], S[ks][3]};
        const float4 v1 = {S[ks][4], S[ks][5], S[ks][6], S[ks][7]};
        *(float4*)(so + j0)     = v0;
        *(float4*)(so + j0 + 4) = v1;
    }
}

// ---------------------------------------------------------------------------
extern "C" void kernel_launch(void* const* d_in, const int* in_sizes, int n_in,
                              void* d_out, int out_size, void* d_ws, size_t ws_size,
                              hipStream_t stream) {
    const float* x     = (const float*)d_in[0];
    const float* state = (const float*)d_in[1];
    const float* Wq    = (const float*)d_in[2];
    const float* Wk    = (const float*)d_in[3];
    const float* Wv    = (const float*)d_in[4];
    const float* Wa    = (const float*)d_in[5];
    const float* ba    = (const float*)d_in[6];
    const float* Wb    = (const float*)d_in[7];
    const float* bb    = (const float*)d_in[8];
    const float* Wo    = (const float*)d_in[9];

    __bf16* Qb    = (__bf16*)d_ws;               // NQ bf16 (raw q, preserved)
    __bf16* Kbf   = Qb + (size_t)NQ;             // NQ bf16 (raw k)
    __bf16* Vbf   = Kbf + (size_t)NQ;            // NQ bf16 (v -> Y_intra -> Y)
    float*  DS    = (float*)(Vbf + (size_t)NQ);  // NQ fp32 (dS^T)
    float*  AlphaT= DS + (size_t)NQ;             // [NH][NROWS]
    float*  BetaT = AlphaT + (size_t)NROWS * NH;
    float*  ExpT  = BetaT + (size_t)NROWS * NH;  // [NH][NROWS] exp(la_t)
    float*  Dec   = ExpT + (size_t)NROWS * NH;   // per-chunk decay
    __bf16* xb    = (__bf16*)(Dec + (size_t)B_SZ * NH * NCH);
    __bf16* WqT   = xb + (size_t)NQ;             // [WqT|WkT|WvT] contiguous
    __bf16* WkT   = WqT + (size_t)DM * INNER;
    __bf16* WvT   = WkT + (size_t)DM * INNER;
    __bf16* WoT   = WvT + (size_t)DM * INNER;

    float* out  = (float*)d_out;                // (B,T,DM)
    float* Sout = out + (size_t)NQ;             // (B,H,D,D)

    // 0) weights cast+transpose
    wt_cast_transpose<<<dim3(16, 16, 4), 256, 0, stream>>>(Wq, Wk, Wv, Wo,
                                                           WqT, WkT, WvT, WoT);
    // 1) fused gates (MFMA) + x->bf16 cast -- 256 blocks, full GPU
    gates_fused<<<NROWS / 32, 256, 0, stream>>>(x, Wa, ba, Wb, bb,
                                                AlphaT, BetaT, xb);
    // 2) Q/K/V projections: r3-verified pipeline, 2 blocks/CU
    qkv_gemm_8ph<<<768, 256, 0, stream>>>(xb, WqT, Qb);
    // 3) intra-chunk MFMA (+fused knorm): Y_intra -> Vbf, dS^T -> DS
    chunk_ds<<<B_SZ * NH * NCH, 256, 0, stream>>>(Qb, Kbf, Vbf, AlphaT, BetaT,
                                                  Dec, DS, ExpT);
    // 4) fused inter-chunk scan + Y_inter finalize (in-register state)
    state_y<<<B_SZ * NH * 4, 256, 0, stream>>>(Qb, DS, Dec, ExpT, state,
                                               Sout, Vbf);
    // 5) output projection: r3-verified pipeline
    out_gemm_8ph<<<256, 256, 0, stream>>>(Vbf, WoT, out);
}

// Round 7
// 238.894 us; speedup vs baseline: 1.1360x; 1.0724x over previous
//
#include <hip/hip_runtime.h>
#include <hip/hip_bf16.h>
#include <math.h>

// Problem constants
#define B_SZ   4
#define T_LEN  2048
#define DM     1024
#define NH     16
#define DH     64
#define INNER  1024          // NH*DH
#define NROWS  (B_SZ*T_LEN)  // 8192
#define NQ     (NROWS*INNER) // elements per Q/K/V/Y buffer
#define CH     64            // chunk length
#define NCH    (T_LEN/CH)    // 32 chunks

typedef __bf16 bf16x8 __attribute__((ext_vector_type(8)));
typedef __bf16 bf16x4 __attribute__((ext_vector_type(4)));
typedef float  f32x4  __attribute__((ext_vector_type(4)));
typedef __attribute__((address_space(3))) void*       lds_vp;
typedef const __attribute__((address_space(1))) void* gbl_vp;

// Swizzled index into a 64x64 bf16 LDS tile: 8-elem blocks rotated by row>>2.
__device__ __forceinline__ int swz(int row, int col) {
    return (row << 6) + ((((col >> 3) + (row >> 2)) & 7) << 3) + (col & 7);
}

// ---------------------------------------------------------------------------
// Weight transpose + cast: W (K x N fp32, row-major) -> WT (N x K bf16).
// ---------------------------------------------------------------------------
__global__ __launch_bounds__(256) void wt_cast_transpose(const float* __restrict__ Wq,
                                                         const float* __restrict__ Wk,
                                                         const float* __restrict__ Wv,
                                                         const float* __restrict__ Wo,
                                                         __bf16* __restrict__ WqT,
                                                         __bf16* __restrict__ WkT,
                                                         __bf16* __restrict__ WvT,
                                                         __bf16* __restrict__ WoT) {
    __shared__ float tile[64][65];
    const float* W;
    __bf16* WT;
    if      (blockIdx.z == 0) { W = Wq; WT = WqT; }
    else if (blockIdx.z == 1) { W = Wk; WT = WkT; }
    else if (blockIdx.z == 2) { W = Wv; WT = WvT; }
    else                      { W = Wo; WT = WoT; }

    const int k0 = blockIdx.y * 64, n0 = blockIdx.x * 64;
    const int tr  = threadIdx.x >> 4;        // 0..15
    const int tc4 = (threadIdx.x & 15) * 4;  // 0..60

#pragma unroll
    for (int r = 0; r < 4; r++) {
        const int k = tr + 16 * r;
        const float4 v = *(const float4*)(W + (size_t)(k0 + k) * DM + n0 + tc4);
        tile[k][tc4 + 0] = v.x;
        tile[k][tc4 + 1] = v.y;
        tile[k][tc4 + 2] = v.z;
        tile[k][tc4 + 3] = v.w;
    }
    __syncthreads();
#pragma unroll
    for (int r = 0; r < 4; r++) {
        const int n = tr + 16 * r;
        bf16x4 o;
#pragma unroll
        for (int j = 0; j < 4; j++) o[j] = (__bf16)tile[tc4 + j][n];
        *(bf16x4*)(WT + (size_t)(n0 + n) * DM + k0 + tc4) = o;
    }
}

// ---------------------------------------------------------------------------
// 3-stage pipelined bf16 MFMA GEMM, 256x128 tile (r3 verified: 886 TF,
// 0 bank conflicts, 2 blocks/CU).
// ---------------------------------------------------------------------------
#define STAGE_STRIDE 24576          // A 16384 + B 8192 bytes
#define B_BASE 16384

template <typename CT>
__device__ __forceinline__ void gemm_pipe_body(const __bf16* __restrict__ A,
                                               const __bf16* __restrict__ BT,
                                               CT* __restrict__ C,
                                               int m0, int n0bt, int n0c) {
    __shared__ __align__(16) char lds[3 * STAGE_STRIDE];

    const int tid  = threadIdx.x;
    const int wid  = tid >> 6;       // 0..3
    const int lane = tid & 63;
    const int wm = wid >> 1;         // 0..1 : 128-row stripe
    const int wn = wid & 1;          // 0..1 : 64-col stripe
    const int frow = lane & 15, quad = lane >> 4;

    // swizzled ds_read byte offsets within one stage (loop-invariant)
    int offA[8], offB[4];
#pragma unroll
    for (int i = 0; i < 8; ++i) {
        const int ra = wm * 128 + i * 16 + frow;
        offA[i] = ra * 64 + ((quad ^ ((ra >> 1) & 3)) << 4);
    }
#pragma unroll
    for (int j = 0; j < 4; ++j) {
        const int rb = wn * 64 + j * 16 + frow;
        offB[j] = B_BASE + rb * 64 + ((quad ^ ((rb >> 1) & 3)) << 4);
    }

    // staging: per-lane pre-swizzled global source (16 rows x 64B per instr)
    const int lr = lane >> 2;                                  // row in region
    const int cs = ((lane & 3) ^ ((lane >> 3) & 3)) << 3;      // elem col (swz)
    const __bf16* gA[4];
#pragma unroll
    for (int q = 0; q < 4; ++q)
        gA[q] = A + (size_t)(m0 + wid * 64 + q * 16 + lr) * 1024 + cs;
    const __bf16* gB[2];
#pragma unroll
    for (int q = 0; q < 2; ++q)
        gB[q] = BT + (size_t)(n0bt + wid * 32 + q * 16 + lr) * 1024 + cs;

    // one staging group: 6 global_load_lds per wave (4 A + 2 B regions)
#define STG(t_, b_) do {                                                           \
        _Pragma("unroll")                                                          \
        for (int q_ = 0; q_ < 4; ++q_)                                             \
            __builtin_amdgcn_global_load_lds((gbl_vp)(gA[q_] + (size_t)(t_) * 32), \
                (lds_vp)(lds + (b_) * STAGE_STRIDE + (wid * 64 + q_ * 16) * 64),   \
                16, 0, 0);                                                         \
        _Pragma("unroll")                                                          \
        for (int q_ = 0; q_ < 2; ++q_)                                             \
            __builtin_amdgcn_global_load_lds((gbl_vp)(gB[q_] + (size_t)(t_) * 32), \
                (lds_vp)(lds + (b_) * STAGE_STRIDE + B_BASE + (wid * 32 + q_ * 16) * 64), \
                16, 0, 0);                                                         \
    } while (0)

#define VM6 asm volatile("s_waitcnt vmcnt(6)" ::: "memory")
#define VM0 asm volatile("s_waitcnt vmcnt(0)" ::: "memory")

    f32x4 acc[8][4];
#pragma unroll
    for (int i = 0; i < 8; i++)
#pragma unroll
        for (int j = 0; j < 4; j++) acc[i][j] = (f32x4)0.f;

    // prologue: stage K-tiles 0,1 (12 loads/wave in flight); wait tile 0
    STG(0, 0); STG(1, 1);
    VM6;
    asm volatile("s_barrier" ::: "memory");

    // one phase: ds_read frags || prefetch issue -> bar -> lgkm0 -> MFMA -> vm -> bar
#define PH(b_, STG_STMT, VM_STMT)                                                  \
    {                                                                              \
        const char* Sb_ = lds + (b_) * STAGE_STRIDE;                               \
        bf16x8 af_[8], bfr_[4];                                                    \
        _Pragma("unroll")                                                          \
        for (int i_ = 0; i_ < 8; ++i_) af_[i_]  = *(const bf16x8*)(Sb_ + offA[i_]);\
        _Pragma("unroll")                                                          \
        for (int j_ = 0; j_ < 4; ++j_) bfr_[j_] = *(const bf16x8*)(Sb_ + offB[j_]);\
        STG_STMT;                                                                  \
        asm volatile("s_barrier" ::: "memory");                                    \
        asm volatile("s_waitcnt lgkmcnt(0)" ::: "memory");                         \
        __builtin_amdgcn_sched_barrier(0);                                         \
        __builtin_amdgcn_s_setprio(1);                                             \
        _Pragma("unroll")                                                          \
        for (int mi_ = 0; mi_ < 8; ++mi_)                                          \
            _Pragma("unroll")                                                      \
            for (int nj_ = 0; nj_ < 4; ++nj_)                                      \
                acc[mi_][nj_] = __builtin_amdgcn_mfma_f32_16x16x32_bf16(           \
                    af_[mi_], bfr_[nj_], acc[mi_][nj_], 0, 0, 0);                  \
        __builtin_amdgcn_s_setprio(0);                                             \
        VM_STMT;                                                                   \
        asm volatile("s_barrier" ::: "memory");                                    \
    }

    // main loop: phases 0..29; phase p stages K-tile p+2.
    for (int u = 0; u < 10; ++u) {
        const int p = 3 * u;
        PH(0, STG(p + 2, 2), VM6);
        PH(1, STG(p + 3, 0), VM6);
        PH(2, STG(p + 4, 1), VM6);
    }
    // phases 30,31: drain
    PH(0, , VM0);
    PH(1, , );

#undef PH
#undef STG
#undef VM6
#undef VM0

    // epilogue: C-write
    const int cr = quad * 4, cc = frow;
#pragma unroll
    for (int mi = 0; mi < 8; ++mi) {
#pragma unroll
        for (int nj = 0; nj < 4; ++nj) {
            CT* Cp = C + (size_t)(m0 + wm * 128 + mi * 16 + cr) * 1024
                       + n0c + wn * 64 + nj * 16 + cc;
#pragma unroll
            for (int r = 0; r < 4; r++) Cp[(size_t)r * 1024] = (CT)acc[mi][nj][r];
        }
    }
}

// ---------------------------------------------------------------------------
// 128x128-tile variant of the same pipeline (for the output projection):
// 512 blocks -> 2 blocks/CU over the FULL machine in one paired round
// (the 256x128 body gave only 256 blocks = 1/CU, no cross-block overlap).
// 4 waves (2M x 2N), per-wave 64x64; stage = A 8KB + B 8KB; groups of 4
// loads -> vmcnt(4); identical swizzle + K-order (bit-identical results).
// ---------------------------------------------------------------------------
#define STAGE2 16384
#define B_BASE2 8192

__device__ __forceinline__ void gemm_pipe128_body(const __bf16* __restrict__ A,
                                                  const __bf16* __restrict__ BT,
                                                  float* __restrict__ C,
                                                  int m0, int n0bt, int n0c) {
    __shared__ __align__(16) char lds[3 * STAGE2];

    const int tid  = threadIdx.x;
    const int wid  = tid >> 6;       // 0..3
    const int lane = tid & 63;
    const int wm = wid >> 1;         // 0..1 : 64-row stripe
    const int wn = wid & 1;          // 0..1 : 64-col stripe
    const int frow = lane & 15, quad = lane >> 4;

    int offA[4], offB[4];
#pragma unroll
    for (int j = 0; j < 4; ++j) {
        const int ra = wm * 64 + j * 16 + frow;
        offA[j] = ra * 64 + ((quad ^ ((ra >> 1) & 3)) << 4);
        const int rb = wn * 64 + j * 16 + frow;
        offB[j] = B_BASE2 + rb * 64 + ((quad ^ ((rb >> 1) & 3)) << 4);
    }

    const int lr = lane >> 2;
    const int cs = ((lane & 3) ^ ((lane >> 3) & 3)) << 3;
    const __bf16* gA[2];
    const __bf16* gB[2];
#pragma unroll
    for (int q = 0; q < 2; ++q) {
        gA[q] = A  + (size_t)(m0 + wid * 32 + q * 16 + lr) * 1024 + cs;
        gB[q] = BT + (size_t)(n0bt + wid * 32 + q * 16 + lr) * 1024 + cs;
    }

#define STG2(t_, b_) do {                                                          \
        _Pragma("unroll")                                                          \
        for (int q_ = 0; q_ < 2; ++q_)                                             \
            __builtin_amdgcn_global_load_lds((gbl_vp)(gA[q_] + (size_t)(t_) * 32), \
                (lds_vp)(lds + (b_) * STAGE2 + (wid * 32 + q_ * 16) * 64),         \
                16, 0, 0);                                                         \
        _Pragma("unroll")                                                          \
        for (int q_ = 0; q_ < 2; ++q_)                                             \
            __builtin_amdgcn_global_load_lds((gbl_vp)(gB[q_] + (size_t)(t_) * 32), \
                (lds_vp)(lds + (b_) * STAGE2 + B_BASE2 + (wid * 32 + q_ * 16) * 64), \
                16, 0, 0);                                                         \
    } while (0)

#define VM4 asm volatile("s_waitcnt vmcnt(4)" ::: "memory")
#define VM0 asm volatile("s_waitcnt vmcnt(0)" ::: "memory")

    f32x4 acc[4][4];
#pragma unroll
    for (int i = 0; i < 4; i++)
#pragma unroll
        for (int j = 0; j < 4; j++) acc[i][j] = (f32x4)0.f;

    STG2(0, 0); STG2(1, 1);
    VM4;
    asm volatile("s_barrier" ::: "memory");

#define PH2(b_, STG_STMT, VM_STMT)                                                 \
    {                                                                              \
        const char* Sb_ = lds + (b_) * STAGE2;                                     \
        bf16x8 af_[4], bfr_[4];                                                    \
        _Pragma("unroll")                                                          \
        for (int j_ = 0; j_ < 4; ++j_) {                                           \
            af_[j_]  = *(const bf16x8*)(Sb_ + offA[j_]);                           \
            bfr_[j_] = *(const bf16x8*)(Sb_ + offB[j_]);                           \
        }                                                                          \
        STG_STMT;                                                                  \
        asm volatile("s_barrier" ::: "memory");                                    \
        asm volatile("s_waitcnt lgkmcnt(0)" ::: "memory");                         \
        __builtin_amdgcn_sched_barrier(0);                                         \
        __builtin_amdgcn_s_setprio(1);                                             \
        _Pragma("unroll")                                                          \
        for (int mi_ = 0; mi_ < 4; ++mi_)                                          \
            _Pragma("unroll")                                                      \
            for (int nj_ = 0; nj_ < 4; ++nj_)                                      \
                acc[mi_][nj_] = __builtin_amdgcn_mfma_f32_16x16x32_bf16(           \
                    af_[mi_], bfr_[nj_], acc[mi_][nj_], 0, 0, 0);                  \
        __builtin_amdgcn_s_setprio(0);                                             \
        VM_STMT;                                                                   \
        asm volatile("s_barrier" ::: "memory");                                    \
    }

    for (int u = 0; u < 10; ++u) {
        const int p = 3 * u;
        PH2(0, STG2(p + 2, 2), VM4);
        PH2(1, STG2(p + 3, 0), VM4);
        PH2(2, STG2(p + 4, 1), VM4);
    }
    PH2(0, , VM0);
    PH2(1, , );

#undef PH2
#undef STG2
#undef VM4
#undef VM0

    const int cr = quad * 4, cc = frow;
#pragma unroll
    for (int mi = 0; mi < 4; ++mi) {
#pragma unroll
        for (int nj = 0; nj < 4; ++nj) {
            float* Cp = C + (size_t)(m0 + wm * 64 + mi * 16 + cr) * 1024
                          + n0c + wn * 64 + nj * 16 + cc;
#pragma unroll
            for (int r = 0; r < 4; r++) Cp[(size_t)r * 1024] = acc[mi][nj][r];
        }
    }
}

// Fused QKV: BTall = [WqT|WkT|WvT] as [3072][1024]; QKV = [Q|K|V] contiguous.
// 768 blocks = 32 m-tiles x 24 n-tiles; 2 blocks/CU resident.
__global__ __launch_bounds__(256, 2) void qkv_gemm_8ph(const __bf16* __restrict__ xb,
                                                       const __bf16* __restrict__ BTall,
                                                       __bf16* __restrict__ QKV) {
    const int id = blockIdx.x;
    const int wg = (id & 7) * 96 + (id >> 3);
    const int mt = wg / 24, nt = wg % 24;
    const int mat = nt >> 3;
    gemm_pipe_body<__bf16>(xb, BTall, QKV + (size_t)mat * NQ,
                           mt * 256, nt * 128, (nt & 7) * 128);
}

// Output projection: 128x128 tiles -> 64 x 8 = 512 blocks, 2/CU, one
// fully-paired round.  XCD swizzle bijective (512 % 8 == 0).
__global__ __launch_bounds__(256, 2) void out_gemm_128(const __bf16* __restrict__ Yb,
                                                       const __bf16* __restrict__ WoT,
                                                       float* __restrict__ Cout) {
    const int id = blockIdx.x;
    const int wg = (id & 7) * 64 + (id >> 3);
    const int mt = wg >> 3, nt = wg & 7;
    gemm_pipe128_body(Yb, WoT, Cout, mt * 128, nt * 128, nt * 128);
}

// ---------------------------------------------------------------------------
// Fused gates + x cast (MFMA).  256 blocks x 256 thr; block = 32 rows.
// ---------------------------------------------------------------------------
#define WGS  1032  // lWg row stride (bf16): 516 dw, 4-dw bank rotation
#define LAS2 72    // lA row stride (bf16): 36 dw -> 4-bank row rotation (2-way free)
__global__ __launch_bounds__(256) void gates_fused(const float* __restrict__ x,
                                                   const float* __restrict__ Wa,
                                                   const float* __restrict__ ba,
                                                   const float* __restrict__ Wb,
                                                   const float* __restrict__ bb,
                                                   float* __restrict__ AlphaT,
                                                   float* __restrict__ BetaT,
                                                   __bf16* __restrict__ xb) {
    __shared__ __align__(16) __bf16 lWg[32 * WGS];
    __shared__ __align__(16) __bf16 lA[32 * LAS2];

    const int tid = threadIdx.x;
    const int wid = tid >> 6, lane = tid & 63;
    const int quad = lane >> 4, frow = lane & 15;
    const int rh = wid >> 1, ct = wid & 1;
    const int m0 = blockIdx.x * 32;

    // ---- stage W^T (bf16) into LDS ----
    {
        const int kbase = tid * 4;
#pragma unroll
        for (int j = 0; j < 4; j++) {
            const int k = kbase + j;
            const float4* war = (const float4*)(Wa + (size_t)k * NH);
            const float4* wbr = (const float4*)(Wb + (size_t)k * NH);
#pragma unroll
            for (int q = 0; q < 4; q++) {
                const float4 a = war[q], bq = wbr[q];
                lWg[(q * 4 + 0) * WGS + k] = (__bf16)a.x;
                lWg[(q * 4 + 1) * WGS + k] = (__bf16)a.y;
                lWg[(q * 4 + 2) * WGS + k] = (__bf16)a.z;
                lWg[(q * 4 + 3) * WGS + k] = (__bf16)a.w;
                lWg[(16 + q * 4 + 0) * WGS + k] = (__bf16)bq.x;
                lWg[(16 + q * 4 + 1) * WGS + k] = (__bf16)bq.y;
                lWg[(16 + q * 4 + 2) * WGS + k] = (__bf16)bq.z;
                lWg[(16 + q * 4 + 3) * WGS + k] = (__bf16)bq.w;
            }
        }
    }
    const float bias = (ct == 0) ? ba[frow] : bb[frow];

    // ---- pipelined K loop: 16 iters of K=64 ----
    const int rrow = tid >> 3;          // 0..31
    const int rk   = (tid & 7) * 8;     // 0..56
    const float* xrow = x + (size_t)(m0 + rrow) * DM + rk;
    float4 c0 = *(const float4*)(xrow + 0);
    float4 c1 = *(const float4*)(xrow + 4);

    f32x4 acc = (f32x4)0.f;

    for (int k0 = 0; k0 < DM; k0 += 64) {
        __syncthreads();   // prev iter's lA reads done (also covers lWg stage)
        bf16x8 xv;
        xv[0] = (__bf16)c0.x; xv[1] = (__bf16)c0.y; xv[2] = (__bf16)c0.z; xv[3] = (__bf16)c0.w;
        xv[4] = (__bf16)c1.x; xv[5] = (__bf16)c1.y; xv[6] = (__bf16)c1.z; xv[7] = (__bf16)c1.w;
        *(bf16x8*)&lA[rrow * LAS2 + rk] = xv;
        *(bf16x8*)(xb + (size_t)(m0 + rrow) * DM + k0 + rk) = xv;
        if (k0 + 64 < DM) {
            c0 = *(const float4*)(xrow + k0 + 64);
            c1 = *(const float4*)(xrow + k0 + 68);
        }
        __syncthreads();
#pragma unroll
        for (int ks = 0; ks < 2; ks++) {
            const bf16x8 af = *(const bf16x8*)&lA[(rh * 16 + frow) * LAS2 + ks * 32 + quad * 8];
            const bf16x8 bf = *(const bf16x8*)&lWg[(ct * 16 + frow) * WGS + k0 + ks * 32 + quad * 8];
            acc = __builtin_amdgcn_mfma_f32_16x16x32_bf16(af, bf, acc, 0, 0, 0);
        }
    }

    // ---- sigmoid epilogue, transposed store ----
    float* dst = (ct == 0) ? AlphaT : BetaT;
#pragma unroll
    for (int r = 0; r < 4; r++) {
        const int row = m0 + rh * 16 + quad * 4 + r;
        const float s = acc[r] + bias;
        dst[(size_t)frow * NROWS + row] = 1.f / (1.f + __expf(-s));
    }
}

// ---------------------------------------------------------------------------
// Pass A (MFMA, bf16 I/O): per (b,h,c), 256 threads = 4 waves.
//   Ab aliases Qb (Qb dead after G-phase) -> LDS 32.75KB -> 4 blocks/CU.
// ---------------------------------------------------------------------------
__global__ __launch_bounds__(256) void chunk_ds(const __bf16* __restrict__ Q,
                                                const __bf16* __restrict__ K,
                                                __bf16* __restrict__ V,
                                                const float* __restrict__ AlphaT,
                                                const float* __restrict__ BetaT,
                                                float* __restrict__ Dec,
                                                float* __restrict__ DS,
                                                float* __restrict__ ExpT) {
    __shared__ __align__(16) __bf16 Qb[64 * 64];   // later reused as Ab
    __shared__ __align__(16) __bf16 Kb[64 * 64];
    __shared__ __align__(16) __bf16 KTs[64 * 64];  // [j][s] = swd_s * kn[s][j]
    __shared__ __align__(16) __bf16 VTb[64 * 64];  // [i][s] = V[s][i]
    __shared__ float sla[64], sb[64], swd[64];
    __bf16* Ab = Qb;                               // alias: Qb dead post-G

    const int blk = blockIdx.x;
    const int c = blk & 31, h = (blk >> 5) & 15, b = blk >> 9;
    const int t0 = c * CH;
    const int tid = threadIdx.x;
    const int wid = tid >> 6, lane = tid & 63;
    const size_t rowbase = ((size_t)(b * T_LEN + t0) * NH + h) * DH;

    // prefetch (16B bf16x8 per matrix per round)
    const int srow = tid >> 3;          // 0..31
    const int scol = (tid & 7) * 8;     // 0..56
    bf16x8 q8[2], k8[2], v8[2];
#pragma unroll
    for (int r = 0; r < 2; r++) {
        const size_t g = rowbase + (size_t)(srow + 32 * r) * INNER + scol;
        q8[r] = *(const bf16x8*)(Q + g);
        k8[r] = *(const bf16x8*)(K + g);
        v8[r] = *(const bf16x8*)(V + g);
    }

    // gates: prefix-sum of log(alpha) over the chunk (wave 0, coalesced)
    if (tid < 64) {
        const int t = tid;
        const size_t gaT = (size_t)h * NROWS + b * T_LEN + t0 + t;
        const float a  = AlphaT[gaT];
        const float bt = BetaT[gaT];
        float xx = logf(a);
#pragma unroll
        for (int off = 1; off < 64; off <<= 1) {
            const float y = __shfl_up(xx, off, 64);
            if (t >= off) xx += y;
        }
        const float la63 = __shfl(xx, 63, 64);
        sla[t] = xx;
        sb[t]  = bt;
        swd[t] = bt * __expf(la63 - xx);
        ExpT[gaT] = __expf(xx);
        if (t == 63) Dec[(size_t)(b * NH + h) * NCH + c] = __expf(la63);
    }
    __syncthreads();

    // stage to LDS: normalize k rows (8 lanes per row -> 3 shfl_xor)
#pragma unroll
    for (int r = 0; r < 2; r++) {
        const int row = srow + 32 * r;
        float kf[8];
        float ss = 0.f;
#pragma unroll
        for (int j = 0; j < 8; j++) { kf[j] = (float)k8[r][j]; ss += kf[j] * kf[j]; }
        ss += __shfl_xor(ss, 1, 64);
        ss += __shfl_xor(ss, 2, 64);
        ss += __shfl_xor(ss, 4, 64);
        const float scale = 1.f / fmaxf(sqrtf(ss), 1e-12f);
        const float w = swd[row];
        bf16x8 kn8;
#pragma unroll
        for (int j = 0; j < 8; j++) {
            const float kn = kf[j] * scale;
            kn8[j] = (__bf16)kn;
            KTs[swz(scol + j, row)] = (__bf16)(w * kn);
            VTb[swz(scol + j, row)] = v8[r][j];
        }
        *(bf16x8*)&Qb[swz(row, scol)] = q8[r];
        *(bf16x8*)&Kb[swz(row, scol)] = kn8;
    }
    __syncthreads();

    const int quad = lane >> 4;
    const int frow = lane & 15;
    const int tw = wid * 16;   // this wave's 16-row output stripe

    // ---- G = Q K^T ----
    f32x4 accG[4];
#pragma unroll
    for (int i = 0; i < 4; i++) accG[i] = (f32x4)0.f;
#pragma unroll
    for (int ks = 0; ks < 2; ks++) {
        const int ko = quad * 8 + 32 * ks;
        const bf16x8 aq = *(const bf16x8*)&Qb[swz(tw + frow, ko)];
#pragma unroll
        for (int st = 0; st < 4; st++) {
            const bf16x8 bk = *(const bf16x8*)&Kb[swz(st * 16 + frow, ko)];
            accG[st] = __builtin_amdgcn_mfma_f32_16x16x32_bf16(aq, bk, accG[st], 0, 0, 0);
        }
    }
    // all waves done reading Qb before Ab (=Qb) writes
    __syncthreads();
    // ---- mask -> Ab (C layout: row=quad*4+r, col=frow) ----
#pragma unroll
    for (int st = 0; st < 4; st++) {
#pragma unroll
        for (int r = 0; r < 4; r++) {
            const int t = tw + quad * 4 + r;
            const int s = st * 16 + frow;
            const float av = (s <= t) ? __expf(sla[t] - sla[s]) * sb[s] * accG[st][r] : 0.f;
            Ab[swz(t, s)] = (__bf16)av;
        }
    }
    __syncthreads();

    // ---- Y_intra = A V  and  dS^T = KTs * VT^T (A/B swapped -> [j][i]) ----
    f32x4 accY[4], accD[4];
#pragma unroll
    for (int i = 0; i < 4; i++) { accY[i] = (f32x4)0.f; accD[i] = (f32x4)0.f; }
#pragma unroll
    for (int ks = 0; ks < 2; ks++) {
        const int ko = quad * 8 + 32 * ks;
        const bf16x8 aA = *(const bf16x8*)&Ab[swz(tw + frow, ko)];
        const bf16x8 aK = *(const bf16x8*)&KTs[swz(tw + frow, ko)];
#pragma unroll
        for (int jt = 0; jt < 4; jt++) {
            const bf16x8 bv = *(const bf16x8*)&VTb[swz(jt * 16 + frow, ko)];
            accY[jt] = __builtin_amdgcn_mfma_f32_16x16x32_bf16(aA, bv, accY[jt], 0, 0, 0);
            accD[jt] = __builtin_amdgcn_mfma_f32_16x16x32_bf16(aK, bv, accD[jt], 0, 0, 0);
        }
    }
    // write Y_intra (bf16) over V, dS^T (fp32) to DS (row slot = j, col = i)
#pragma unroll
    for (int jt = 0; jt < 4; jt++) {
#pragma unroll
        for (int r = 0; r < 4; r++) {
            const int row = tw + quad * 4 + r;
            const size_t g = rowbase + (size_t)row * INNER + jt * 16 + frow;
            V[g]  = (__bf16)accY[jt][r];
            DS[g] = accD[jt][r];
        }
    }
}

// ---------------------------------------------------------------------------
// Fused inter-chunk scan + Y_inter (in-register state).
//   Block remap: the 4 iq blocks of one (b,h) share the same XCD (id & 7
//   preserved) so the shared Q chunk is fetched once per XCD L2, not 4x.
// ---------------------------------------------------------------------------
__global__ __launch_bounds__(256) void state_y(const __bf16* __restrict__ Q,
                                               const float* __restrict__ DS,
                                               const float* __restrict__ Dec,
                                               const float* __restrict__ ExpT,
                                               const float* __restrict__ state_in,
                                               float* __restrict__ state_out,
                                               __bf16* __restrict__ Yb) {
    const int p = blockIdx.x;            // 0..255
    const int xcd = p & 7, idx = p >> 3; // hw heuristic: xcd = id % 8
    const int bh = xcd * 8 + (idx >> 2); // 4 consecutive-iq blocks keep same xcd
    const int iq = idx & 3;
    const int b = bh >> 4, h = bh & 15;
    const int tid = threadIdx.x;
    const int wid = tid >> 6, lane = tid & 63;
    const int frow = lane & 15, quad = lane >> 4;
    const int tw = wid * 16;
    const int i = iq * 16 + frow;          // this lane's state column

    // init state slice: S[ks][e] = state[b,h,i, j=32ks+quad*8+e]
    float S[2][8];
    {
        const float* st = state_in + ((size_t)((b * NH + h) * DH) + i) * DH;
#pragma unroll
        for (int ks = 0; ks < 2; ks++) {
            const int j0 = 32 * ks + quad * 8;
            const float4 a = *(const float4*)(st + j0);
            const float4 d = *(const float4*)(st + j0 + 4);
            S[ks][0] = a.x; S[ks][1] = a.y; S[ks][2] = a.z; S[ks][3] = a.w;
            S[ks][4] = d.x; S[ks][5] = d.y; S[ks][6] = d.z; S[ks][7] = d.w;
        }
    }

    const size_t bhs = (size_t)(b * NH + h);
#pragma unroll 2
    for (int c = 0; c < NCH; c++) {
        const int t0 = c * CH;
        const size_t rowbase = ((size_t)(b * T_LEN + t0) * NH + h) * DH;
        const float decay = Dec[bhs * NCH + c];

        // Q A-fragments first (MFMA's only memory dependency)
        const bf16x8 aq0 = *(const bf16x8*)(Q + rowbase + (size_t)(tw + frow) * INNER + quad * 8);
        const bf16x8 aq1 = *(const bf16x8*)(Q + rowbase + (size_t)(tw + frow) * INNER + 32 + quad * 8);

        // dS^T loads (scan-independent; overlap MFMA)
        float ds[2][8];
#pragma unroll
        for (int ks = 0; ks < 2; ks++) {
            const int j0 = 32 * ks + quad * 8;
#pragma unroll
            for (int e = 0; e < 8; e++)
                ds[ks][e] = DS[rowbase + (size_t)(j0 + e) * INNER + i];
        }

        // B-fragments from PRE-update state
        bf16x8 bs0, bs1;
#pragma unroll
        for (int e = 0; e < 8; e++) { bs0[e] = (__bf16)S[0][e]; bs1[e] = (__bf16)S[1][e]; }

        f32x4 acc = (f32x4)0.f;
        acc = __builtin_amdgcn_mfma_f32_16x16x32_bf16(aq0, bs0, acc, 0, 0, 0);
        acc = __builtin_amdgcn_mfma_f32_16x16x32_bf16(aq1, bs1, acc, 0, 0, 0);

        // state scan update (elementwise)
#pragma unroll
        for (int ks = 0; ks < 2; ks++)
#pragma unroll
            for (int e = 0; e < 8; e++)
                S[ks][e] = decay * S[ks][e] + ds[ks][e];

        // Yb RMW: C layout row=quad*4+r (t-sub), col=frow (i)
#pragma unroll
        for (int r = 0; r < 4; r++) {
            const int t = tw + quad * 4 + r;
            const float ee = ExpT[(size_t)h * NROWS + b * T_LEN + t0 + t];
            __bf16* yp = Yb + rowbase + (size_t)t * INNER + i;
            *yp = (__bf16)(ee * acc[r] + (float)*yp);
        }
    }

    // final state (fp32, [i][j]) -- j contiguous per lane -> float4
    float* so = state_out + ((size_t)((b * NH + h) * DH) + i) * DH;
#pragma unroll
    for (int ks = 0; ks < 2; ks++) {
        const int j0 = 32 * ks + quad * 8;
        const float4 v0 = {S[ks][0], S[ks][1], S[ks][2], S[ks][3]};
        const float4 v1 = {S[ks][4], S[ks][5], S[ks][6], S[ks][7]};
        *(float4*)(so + j0)     = v0;
        *(float4*)(so + j0 + 4) = v1;
    }
}

// ---------------------------------------------------------------------------
extern "C" void kernel_launch(void* const* d_in, const int* in_sizes, int n_in,
                              void* d_out, int out_size, void* d_ws, size_t ws_size,
                              hipStream_t stream) {
    const float* x     = (const float*)d_in[0];
    const float* state = (const float*)d_in[1];
    const float* Wq    = (const float*)d_in[2];
    const float* Wk    = (const float*)d_in[3];
    const float* Wv    = (const float*)d_in[4];
    const float* Wa    = (const float*)d_in[5];
    const float* ba    = (const float*)d_in[6];
    const float* Wb    = (const float*)d_in[7];
    const float* bb    = (const float*)d_in[8];
    const float* Wo    = (const float*)d_in[9];

    __bf16* Qb    = (__bf16*)d_ws;               // NQ bf16 (raw q, preserved)
    __bf16* Kbf   = Qb + (size_t)NQ;             // NQ bf16 (raw k)
    __bf16* Vbf   = Kbf + (size_t)NQ;            // NQ bf16 (v -> Y_intra -> Y)
    float*  DS    = (float*)(Vbf + (size_t)NQ);  // NQ fp32 (dS^T)
    float*  AlphaT= DS + (size_t)NQ;             // [NH][NROWS]
    float*  BetaT = AlphaT + (size_t)NROWS * NH;
    float*  ExpT  = BetaT + (size_t)NROWS * NH;  // [NH][NROWS] exp(la_t)
    float*  Dec   = ExpT + (size_t)NROWS * NH;   // per-chunk decay
    __bf16* xb    = (__bf16*)(Dec + (size_t)B_SZ * NH * NCH);
    __bf16* WqT   = xb + (size_t)NQ;             // [WqT|WkT|WvT] contiguous
    __bf16* WkT   = WqT + (size_t)DM * INNER;
    __bf16* WvT   = WkT + (size_t)DM * INNER;
    __bf16* WoT   = WvT + (size_t)DM * INNER;

    float* out  = (float*)d_out;                // (B,T,DM)
    float* Sout = out + (size_t)NQ;             // (B,H,D,D)

    // 0) weights cast+transpose
    wt_cast_transpose<<<dim3(16, 16, 4), 256, 0, stream>>>(Wq, Wk, Wv, Wo,
                                                           WqT, WkT, WvT, WoT);
    // 1) fused gates (MFMA) + x->bf16 cast -- 256 blocks, full GPU
    gates_fused<<<NROWS / 32, 256, 0, stream>>>(x, Wa, ba, Wb, bb,
                                                AlphaT, BetaT, xb);
    // 2) Q/K/V projections: r3-verified pipeline, 2 blocks/CU
    qkv_gemm_8ph<<<768, 256, 0, stream>>>(xb, WqT, Qb);
    // 3) intra-chunk MFMA (+fused knorm): Y_intra -> Vbf, dS^T -> DS
    chunk_ds<<<B_SZ * NH * NCH, 256, 0, stream>>>(Qb, Kbf, Vbf, AlphaT, BetaT,
                                                  Dec, DS, ExpT);
    // 4) fused inter-chunk scan + Y_inter finalize (XCD-affine iq quads)
    state_y<<<B_SZ * NH * 4, 256, 0, stream>>>(Qb, DS, Dec, ExpT, state,
                                               Sout, Vbf);
    // 5) output projection: 128x128 tiles, 512 blocks, full paired machine
    out_gemm_128<<<512, 256, 0, stream>>>(Vbf, WoT, out);
}